// Round 2
// baseline (3648.330 us; speedup 1.0000x reference)
//
#include <hip/hip_runtime.h>

typedef float f32x4 __attribute__((ext_vector_type(4)));

#define T_STEPS 512
#define BATCH   64
#define NIN     512
#define H       1024
#define BH      (BATCH * H)   // 65536

// ---------------------------------------------------------------------------
// Kernel 1: transpose w_rec [j][h] -> wrecT [h][j]  (4 MB, one-time per call)
// ---------------------------------------------------------------------------
__global__ void transpose1024(const float* __restrict__ in, float* __restrict__ out) {
    __shared__ float tile[32][33];
    const int tx = threadIdx.x, ty = threadIdx.y;
    const int xg = blockIdx.x * 32 + tx;
    const int ybase = blockIdx.y * 32;
#pragma unroll
    for (int r = 0; r < 32; r += 8)
        tile[ty + r][tx] = in[(size_t)(ybase + ty + r) * H + xg];
    __syncthreads();
    const int x2 = blockIdx.y * 32 + tx;
    const int y2base = blockIdx.x * 32;
#pragma unroll
    for (int r = 0; r < 32; r += 8)
        out[(size_t)(y2base + ty + r) * H + x2] = tile[tx][ty + r];
}

// ---------------------------------------------------------------------------
// Kernel 2: cur[m][n] = sum_k x[m][k] * w_in[n][k]  (R7-verbatim, untouched)
// ---------------------------------------------------------------------------
#define BM 128
#define BN 128
#define BK 16
#define LDSS 132

__global__ __launch_bounds__(256) void gemm_xwin(const float* __restrict__ x,
                                                 const float* __restrict__ w,
                                                 float* __restrict__ cur) {
    __shared__ __align__(16) float As[BK][LDSS];
    __shared__ __align__(16) float Bs[BK][LDSS];
    const int tid = threadIdx.x;
    const int tx = tid & 15, ty = tid >> 4;
    const int tx4 = tx * 4, ty4 = ty * 4;
    const int m0 = blockIdx.y * BM;
    const int n0 = blockIdx.x * BN;

    float acc[8][8];
#pragma unroll
    for (int i = 0; i < 8; ++i)
#pragma unroll
        for (int j = 0; j < 8; ++j) acc[i][j] = 0.0f;

    const int ar = tid >> 2;
    const int akc = (tid & 3) * 4;

    for (int k0 = 0; k0 < NIN; k0 += BK) {
        const float4 a0 = *reinterpret_cast<const float4*>(&x[(size_t)(m0 + ar) * NIN + k0 + akc]);
        const float4 a1 = *reinterpret_cast<const float4*>(&x[(size_t)(m0 + ar + 64) * NIN + k0 + akc]);
        const float4 b0 = *reinterpret_cast<const float4*>(&w[(size_t)(n0 + ar) * NIN + k0 + akc]);
        const float4 b1 = *reinterpret_cast<const float4*>(&w[(size_t)(n0 + ar + 64) * NIN + k0 + akc]);
        __syncthreads();
        As[akc + 0][ar] = a0.x; As[akc + 1][ar] = a0.y; As[akc + 2][ar] = a0.z; As[akc + 3][ar] = a0.w;
        As[akc + 0][ar + 64] = a1.x; As[akc + 1][ar + 64] = a1.y; As[akc + 2][ar + 64] = a1.z; As[akc + 3][ar + 64] = a1.w;
        Bs[akc + 0][ar] = b0.x; Bs[akc + 1][ar] = b0.y; Bs[akc + 2][ar] = b0.z; Bs[akc + 3][ar] = b0.w;
        Bs[akc + 0][ar + 64] = b1.x; Bs[akc + 1][ar + 64] = b1.y; Bs[akc + 2][ar + 64] = b1.z; Bs[akc + 3][ar + 64] = b1.w;
        __syncthreads();

#pragma unroll
        for (int kk = 0; kk < BK; ++kk) {
            const float4 av0 = *reinterpret_cast<const float4*>(&As[kk][ty4]);
            const float4 av1 = *reinterpret_cast<const float4*>(&As[kk][ty4 + 64]);
            const float4 bv0 = *reinterpret_cast<const float4*>(&Bs[kk][tx4]);
            const float4 bv1 = *reinterpret_cast<const float4*>(&Bs[kk][tx4 + 64]);
            const float ar_[8] = {av0.x, av0.y, av0.z, av0.w, av1.x, av1.y, av1.z, av1.w};
            const float br_[8] = {bv0.x, bv0.y, bv0.z, bv0.w, bv1.x, bv1.y, bv1.z, bv1.w};
#pragma unroll
            for (int i = 0; i < 8; ++i)
#pragma unroll
                for (int j = 0; j < 8; ++j)
                    acc[i][j] = fmaf(ar_[i], br_[j], acc[i][j]);
        }
    }

#pragma unroll
    for (int gi = 0; gi < 2; ++gi)
#pragma unroll
        for (int ii = 0; ii < 4; ++ii) {
            const int i = gi * 4 + ii;
            const int row = m0 + ty4 + ii + gi * 64;
            float* dst = &cur[(size_t)row * H + n0 + tx4];
            *reinterpret_cast<float4*>(dst)      = make_float4(acc[i][0], acc[i][1], acc[i][2], acc[i][3]);
            *reinterpret_cast<float4*>(dst + 64) = make_float4(acc[i][4], acc[i][5], acc[i][6], acc[i][7]);
        }
}

// ---------------------------------------------------------------------------
// Kernel 3: sequential LSNN scan. One block per batch, 256 thr x 4 neurons.
//   R10: R9's merged list kept (one flat spike list, 2 barriers/step), but
//   the gather pipeline is shrunk to fit the register file: 3-deep rotation
//   of 8-row batches (gA/gB/gC[8] = 96 VGPRs, 24 loads in flight) with the
//   masked final batch folded into the rotation (no gT buffer). R9 spilled
//   (VGPR=256 + 1.7 GB scratch writes: gA/gB/gT[16] = 192 VGPRs). All FP
//   math, accumulation order (flat list order == R8's wave 0..3 ascending),
//   ballot/compaction and P-prefetch placement are bit-identical to R8.
// ---------------------------------------------------------------------------
__global__ __launch_bounds__(256, 1) void lsnn_scan_kernel(float* __restrict__ io,
                                                           const float* __restrict__ wrecT) {
    const int b = blockIdx.x;
    const int tid = threadIdx.x;
    const int wave = tid >> 6, lane = tid & 63;
    const int j0 = tid * 4;

    __shared__ __align__(16) int list[2][1024];   // [phase][slot] merged list
    __shared__ __align__(16) int cnt[2][4];       // [phase][wave] per-wave counts

    float sv0 = 0.f, sv1 = 0.f, sv2 = 0.f, sv3 = 0.f;
    float si0 = 0.f, si1 = 0.f, si2 = 0.f, si3 = 0.f;
    float sb0 = 1.f, sb1 = 1.f, sb2 = 1.f, sb3 = 1.f;
    float sz0 = 0.f, sz1 = 0.f, sz2 = 0.f, sz3 = 0.f;
    int p = 0;

    const float C_MEM = (float)(1e-3 * 100.0);
    const float C_SYN = (float)(1e-3 * 200.0);
    const float C_AD  = (float)(1e-3 * (1.0 / 800.0));
    const float BETA  = 1.8f;

    float* base = io + (size_t)b * H + j0;

    if (lane == 0) cnt[0][wave] = 0;
    asm volatile("s_waitcnt lgkmcnt(0)" ::: "memory");
    __builtin_amdgcn_s_barrier();

    // chunk prefetch buffers: 8 steps of cur
    f32x4 P0 = *reinterpret_cast<const f32x4*>(base + (size_t)0 * BH);
    f32x4 P1 = *reinterpret_cast<const f32x4*>(base + (size_t)1 * BH);
    f32x4 P2 = *reinterpret_cast<const f32x4*>(base + (size_t)2 * BH);
    f32x4 P3 = *reinterpret_cast<const f32x4*>(base + (size_t)3 * BH);
    f32x4 P4 = *reinterpret_cast<const f32x4*>(base + (size_t)4 * BH);
    f32x4 P5 = *reinterpret_cast<const f32x4*>(base + (size_t)5 * BH);
    f32x4 P6 = *reinterpret_cast<const f32x4*>(base + (size_t)6 * BH);
    f32x4 P7 = *reinterpret_cast<const f32x4*>(base + (size_t)7 * BH);

// load batch K (rows [8K, 8K+8) of the flat list); rows >= n clamp to row 0
#define LOAD8(BUF, K)                                                         \
  {                                                                           \
    const int A0_ = (K) << 3;                                                 \
    const int4 q0_ = *reinterpret_cast<const int4*>(lst + A0_);               \
    const int4 q1_ = *reinterpret_cast<const int4*>(lst + A0_ + 4);           \
    int h0_ = __builtin_amdgcn_readfirstlane(q0_.x);                          \
    int h1_ = __builtin_amdgcn_readfirstlane(q0_.y);                          \
    int h2_ = __builtin_amdgcn_readfirstlane(q0_.z);                          \
    int h3_ = __builtin_amdgcn_readfirstlane(q0_.w);                          \
    int h4_ = __builtin_amdgcn_readfirstlane(q1_.x);                          \
    int h5_ = __builtin_amdgcn_readfirstlane(q1_.y);                          \
    int h6_ = __builtin_amdgcn_readfirstlane(q1_.z);                          \
    int h7_ = __builtin_amdgcn_readfirstlane(q1_.w);                          \
    h0_ = (A0_ + 0 < n) ? h0_ : 0;  h1_ = (A0_ + 1 < n) ? h1_ : 0;            \
    h2_ = (A0_ + 2 < n) ? h2_ : 0;  h3_ = (A0_ + 3 < n) ? h3_ : 0;            \
    h4_ = (A0_ + 4 < n) ? h4_ : 0;  h5_ = (A0_ + 5 < n) ? h5_ : 0;            \
    h6_ = (A0_ + 6 < n) ? h6_ : 0;  h7_ = (A0_ + 7 < n) ? h7_ : 0;            \
    BUF[0] = *(const f32x4*)(wrecT + (size_t)(unsigned)h0_ * H + j0);         \
    BUF[1] = *(const f32x4*)(wrecT + (size_t)(unsigned)h1_ * H + j0);         \
    BUF[2] = *(const f32x4*)(wrecT + (size_t)(unsigned)h2_ * H + j0);         \
    BUF[3] = *(const f32x4*)(wrecT + (size_t)(unsigned)h3_ * H + j0);         \
    BUF[4] = *(const f32x4*)(wrecT + (size_t)(unsigned)h4_ * H + j0);         \
    BUF[5] = *(const f32x4*)(wrecT + (size_t)(unsigned)h5_ * H + j0);         \
    BUF[6] = *(const f32x4*)(wrecT + (size_t)(unsigned)h6_ * H + j0);         \
    BUF[7] = *(const f32x4*)(wrecT + (size_t)(unsigned)h7_ * H + j0);         \
  }

#define ACC8(BUF)                                                             \
  { _Pragma("unroll")                                                         \
    for (int k_ = 0; k_ < 8; ++k_) {                                          \
      r0 += BUF[k_].x; r1 += BUF[k_].y; r2 += BUF[k_].z; r3 += BUF[k_].w;     \
    } }

#define ACC8M(BUF, K)                                                         \
  { _Pragma("unroll")                                                         \
    for (int k_ = 0; k_ < 8; ++k_) {                                          \
      const float m_ = ((((K) << 3) + k_) < n) ? 1.0f : 0.0f;                 \
      r0 = fmaf(m_, BUF[k_].x, r0); r1 = fmaf(m_, BUF[k_].y, r1);             \
      r2 = fmaf(m_, BUF[k_].z, r2); r3 = fmaf(m_, BUF[k_].w, r3);             \
    } }

// accumulate batch K which may be the final partial batch
#define ACCL(BUF, K)                                                          \
  { if ((((K) + 1) << 3) <= n) { ACC8(BUF) } else { ACC8M(BUF, K) } }

#define SCAN_STEP(T, CREG, PF)                                                \
  {                                                                           \
    const float cc0 = CREG.x, cc1 = CREG.y, cc2 = CREG.z, cc3 = CREG.w;       \
    const int4 cq = *reinterpret_cast<const int4*>(&cnt[p][0]);               \
    const int n = __builtin_amdgcn_readfirstlane(cq.x + cq.y + cq.z + cq.w);  \
    const int nbt = (n + 7) >> 3;                                             \
    const int* lst = &list[p][0];                                             \
    f32x4 gA[8], gB[8], gC[8];                                                \
    float r0 = 0.f, r1 = 0.f, r2 = 0.f, r3 = 0.f;                             \
    /* prologue: issue first three batches before dynamics/ballot */          \
    if (nbt > 0) LOAD8(gA, 0);                                                \
    if (nbt > 1) LOAD8(gB, 1);                                                \
    if (nbt > 2) LOAD8(gC, 2);                                                \
    /* dynamics (independent of this step's gather) */                        \
    const float vd0 = sv0 + C_MEM * (0.0f - sv0 + si0);                       \
    const float vd1 = sv1 + C_MEM * (0.0f - sv1 + si1);                       \
    const float vd2 = sv2 + C_MEM * (0.0f - sv2 + si2);                       \
    const float vd3 = sv3 + C_MEM * (0.0f - sv3 + si3);                       \
    const float id0 = si0 - C_SYN * si0;                                      \
    const float id1 = si1 - C_SYN * si1;                                      \
    const float id2 = si2 - C_SYN * si2;                                      \
    const float id3 = si3 - C_SYN * si3;                                      \
    const float bd0 = sb0 + C_AD * (1.0f - sb0);                              \
    const float bd1 = sb1 + C_AD * (1.0f - sb1);                              \
    const float bd2 = sb2 + C_AD * (1.0f - sb2);                              \
    const float bd3 = sb3 + C_AD * (1.0f - sb3);                              \
    sz0 = ((vd0 - bd0) > 0.0f) ? 1.0f : 0.0f;                                 \
    sz1 = ((vd1 - bd1) > 0.0f) ? 1.0f : 0.0f;                                 \
    sz2 = ((vd2 - bd2) > 0.0f) ? 1.0f : 0.0f;                                 \
    sz3 = ((vd3 - bd3) > 0.0f) ? 1.0f : 0.0f;                                 \
    sv0 = (sz0 > 0.0f) ? 0.0f : vd0;                                          \
    sv1 = (sz1 > 0.0f) ? 0.0f : vd1;                                          \
    sv2 = (sz2 > 0.0f) ? 0.0f : vd2;                                          \
    sv3 = (sz3 > 0.0f) ? 0.0f : vd3;                                          \
    sb0 = (sz0 > 0.0f) ? (bd0 + BETA) : bd0;                                  \
    sb1 = (sz1 > 0.0f) ? (bd1 + BETA) : bd1;                                  \
    sb2 = (sz2 > 0.0f) ? (bd2 + BETA) : bd2;                                  \
    sb3 = (sz3 > 0.0f) ? (bd3 + BETA) : bd3;                                  \
    *reinterpret_cast<f32x4*>(base + (size_t)(T) * BH) =                      \
        (f32x4){sz0, sz1, sz2, sz3};                                          \
    const unsigned long long m0 = __ballot(sz0 > 0.0f);                       \
    const unsigned long long m1 = __ballot(sz1 > 0.0f);                       \
    const unsigned long long m2 = __ballot(sz2 > 0.0f);                       \
    const unsigned long long m3 = __ballot(sz3 > 0.0f);                       \
    unsigned pos = __builtin_amdgcn_mbcnt_hi((unsigned)(m0 >> 32),            \
                   __builtin_amdgcn_mbcnt_lo((unsigned)m0, 0u));              \
    pos = __builtin_amdgcn_mbcnt_hi((unsigned)(m1 >> 32),                     \
          __builtin_amdgcn_mbcnt_lo((unsigned)m1, pos));                      \
    pos = __builtin_amdgcn_mbcnt_hi((unsigned)(m2 >> 32),                     \
          __builtin_amdgcn_mbcnt_lo((unsigned)m2, pos));                      \
    pos = __builtin_amdgcn_mbcnt_hi((unsigned)(m3 >> 32),                     \
          __builtin_amdgcn_mbcnt_lo((unsigned)m3, pos));                      \
    if (lane == 0)                                                            \
      cnt[p ^ 1][wave] = __popcll(m0) + __popcll(m1) + __popcll(m2) + __popcll(m3); \
    asm volatile("s_waitcnt lgkmcnt(0)" ::: "memory");                        \
    __builtin_amdgcn_s_barrier();                                             \
    /* cross-wave prefix -> write entries into merged list */                 \
    const int4 nc = *reinterpret_cast<const int4*>(&cnt[p ^ 1][0]);           \
    const int woff = (wave > 0 ? nc.x : 0) + (wave > 1 ? nc.y : 0) +          \
                     (wave > 2 ? nc.z : 0);                                   \
    int* dst = &list[p ^ 1][woff];                                            \
    if (sz0 > 0.0f) dst[pos++] = j0 + 0;                                      \
    if (sz1 > 0.0f) dst[pos++] = j0 + 1;                                      \
    if (sz2 > 0.0f) dst[pos++] = j0 + 2;                                      \
    if (sz3 > 0.0f) dst[pos++] = j0 + 3;                                      \
    asm volatile("s_waitcnt lgkmcnt(0)" ::: "memory");                        \
    __builtin_amdgcn_s_barrier();                                             \
    /* 3-deep rotating gather pipeline over 8-row batches */                  \
    {                                                                         \
      int kk_ = 0;                                                            \
      while (kk_ + 3 < nbt) {                                                 \
        ACC8(gA) LOAD8(gA, kk_ + 3);                                          \
        ACC8(gB) if (kk_ + 4 < nbt) LOAD8(gB, kk_ + 4);                       \
        ACC8(gC) if (kk_ + 5 < nbt) LOAD8(gC, kk_ + 5);                       \
        kk_ += 3;                                                             \
      }                                                                       \
      if (kk_ < nbt)     ACCL(gA, kk_)                                        \
      if (kk_ + 1 < nbt) ACCL(gB, kk_ + 1)                                    \
      if (kk_ + 2 < nbt) ACCL(gC, kk_ + 2)                                    \
    }                                                                         \
    if (PF) {                                                                 \
      if ((T) + 1 < T_STEPS) {                                                \
        const float* pb = base + (size_t)((T) + 1) * BH;                      \
        P0 = *(const f32x4*)(pb + (size_t)0 * BH);                            \
        P1 = *(const f32x4*)(pb + (size_t)1 * BH);                            \
        P2 = *(const f32x4*)(pb + (size_t)2 * BH);                            \
        P3 = *(const f32x4*)(pb + (size_t)3 * BH);                            \
        P4 = *(const f32x4*)(pb + (size_t)4 * BH);                            \
        P5 = *(const f32x4*)(pb + (size_t)5 * BH);                            \
        P6 = *(const f32x4*)(pb + (size_t)6 * BH);                            \
        P7 = *(const f32x4*)(pb + (size_t)7 * BH);                            \
      }                                                                       \
    }                                                                         \
    si0 = (id0 + cc0) + r0;                                                   \
    si1 = (id1 + cc1) + r1;                                                   \
    si2 = (id2 + cc2) + r2;                                                   \
    si3 = (id3 + cc3) + r3;                                                   \
    p ^= 1;                                                                   \
  }

    for (int t = 0; t < T_STEPS; t += 8) {
        SCAN_STEP(t,     P0, 0);
        SCAN_STEP(t + 1, P1, 0);
        SCAN_STEP(t + 2, P2, 0);
        SCAN_STEP(t + 3, P3, 0);
        SCAN_STEP(t + 4, P4, 0);
        SCAN_STEP(t + 5, P5, 0);
        SCAN_STEP(t + 6, P6, 0);
        SCAN_STEP(t + 7, P7, 1);
    }
#undef SCAN_STEP
#undef ACCL
#undef ACC8M
#undef ACC8
#undef LOAD8

    float* fo = io + (size_t)T_STEPS * BH + (size_t)b * H + j0;
    *reinterpret_cast<float4*>(fo)          = make_float4(sz0, sz1, sz2, sz3);
    *reinterpret_cast<float4*>(fo + BH)     = make_float4(sv0, sv1, sv2, sv3);
    *reinterpret_cast<float4*>(fo + 2 * BH) = make_float4(si0, si1, si2, si3);
    *reinterpret_cast<float4*>(fo + 3 * BH) = make_float4(sb0, sb1, sb2, sb3);
}

// ---------------------------------------------------------------------------
extern "C" void kernel_launch(void* const* d_in, const int* in_sizes, int n_in,
                              void* d_out, int out_size, void* d_ws, size_t ws_size,
                              hipStream_t stream) {
    const float* x     = (const float*)d_in[0];
    const float* w_in  = (const float*)d_in[1];
    const float* w_rec = (const float*)d_in[2];
    float* out   = (float*)d_out;
    float* wrecT = (float*)d_ws;

    transpose1024<<<dim3(H / 32, H / 32), dim3(32, 8), 0, stream>>>(w_rec, wrecT);
    gemm_xwin<<<dim3(H / BN, (T_STEPS * BATCH) / BM), 256, 0, stream>>>(x, w_in, out);
    lsnn_scan_kernel<<<BATCH, 256, 0, stream>>>(out, wrecT);
}

// Round 3
// 1016.596 us; speedup vs baseline: 3.5888x; 3.5888x over previous
//
#include <hip/hip_runtime.h>

typedef float f32x4 __attribute__((ext_vector_type(4)));

#define T_STEPS 512
#define BATCH   64
#define NIN     512
#define H       1024
#define BH      (BATCH * H)   // 65536

// ---------------------------------------------------------------------------
// Kernel 1: transpose w_rec [j][h] -> wrecT [h][j]  (4 MB, one-time per call)
// ---------------------------------------------------------------------------
__global__ void transpose1024(const float* __restrict__ in, float* __restrict__ out) {
    __shared__ float tile[32][33];
    const int tx = threadIdx.x, ty = threadIdx.y;
    const int xg = blockIdx.x * 32 + tx;
    const int ybase = blockIdx.y * 32;
#pragma unroll
    for (int r = 0; r < 32; r += 8)
        tile[ty + r][tx] = in[(size_t)(ybase + ty + r) * H + xg];
    __syncthreads();
    const int x2 = blockIdx.y * 32 + tx;
    const int y2base = blockIdx.x * 32;
#pragma unroll
    for (int r = 0; r < 32; r += 8)
        out[(size_t)(y2base + ty + r) * H + x2] = tile[tx][ty + r];
}

// ---------------------------------------------------------------------------
// Kernel 2: cur[m][n] = sum_k x[m][k] * w_in[n][k]  (R7-verbatim, untouched)
// ---------------------------------------------------------------------------
#define BM 128
#define BN 128
#define BK 16
#define LDSS 132

__global__ __launch_bounds__(256) void gemm_xwin(const float* __restrict__ x,
                                                 const float* __restrict__ w,
                                                 float* __restrict__ cur) {
    __shared__ __align__(16) float As[BK][LDSS];
    __shared__ __align__(16) float Bs[BK][LDSS];
    const int tid = threadIdx.x;
    const int tx = tid & 15, ty = tid >> 4;
    const int tx4 = tx * 4, ty4 = ty * 4;
    const int m0 = blockIdx.y * BM;
    const int n0 = blockIdx.x * BN;

    float acc[8][8];
#pragma unroll
    for (int i = 0; i < 8; ++i)
#pragma unroll
        for (int j = 0; j < 8; ++j) acc[i][j] = 0.0f;

    const int ar = tid >> 2;
    const int akc = (tid & 3) * 4;

    for (int k0 = 0; k0 < NIN; k0 += BK) {
        const float4 a0 = *reinterpret_cast<const float4*>(&x[(size_t)(m0 + ar) * NIN + k0 + akc]);
        const float4 a1 = *reinterpret_cast<const float4*>(&x[(size_t)(m0 + ar + 64) * NIN + k0 + akc]);
        const float4 b0 = *reinterpret_cast<const float4*>(&w[(size_t)(n0 + ar) * NIN + k0 + akc]);
        const float4 b1 = *reinterpret_cast<const float4*>(&w[(size_t)(n0 + ar + 64) * NIN + k0 + akc]);
        __syncthreads();
        As[akc + 0][ar] = a0.x; As[akc + 1][ar] = a0.y; As[akc + 2][ar] = a0.z; As[akc + 3][ar] = a0.w;
        As[akc + 0][ar + 64] = a1.x; As[akc + 1][ar + 64] = a1.y; As[akc + 2][ar + 64] = a1.z; As[akc + 3][ar + 64] = a1.w;
        Bs[akc + 0][ar] = b0.x; Bs[akc + 1][ar] = b0.y; Bs[akc + 2][ar] = b0.z; Bs[akc + 3][ar] = b0.w;
        Bs[akc + 0][ar + 64] = b1.x; Bs[akc + 1][ar + 64] = b1.y; Bs[akc + 2][ar + 64] = b1.z; Bs[akc + 3][ar + 64] = b1.w;
        __syncthreads();

#pragma unroll
        for (int kk = 0; kk < BK; ++kk) {
            const float4 av0 = *reinterpret_cast<const float4*>(&As[kk][ty4]);
            const float4 av1 = *reinterpret_cast<const float4*>(&As[kk][ty4 + 64]);
            const float4 bv0 = *reinterpret_cast<const float4*>(&Bs[kk][tx4]);
            const float4 bv1 = *reinterpret_cast<const float4*>(&Bs[kk][tx4 + 64]);
            const float ar_[8] = {av0.x, av0.y, av0.z, av0.w, av1.x, av1.y, av1.z, av1.w};
            const float br_[8] = {bv0.x, bv0.y, bv0.z, bv0.w, bv1.x, bv1.y, bv1.z, bv1.w};
#pragma unroll
            for (int i = 0; i < 8; ++i)
#pragma unroll
                for (int j = 0; j < 8; ++j)
                    acc[i][j] = fmaf(ar_[i], br_[j], acc[i][j]);
        }
    }

#pragma unroll
    for (int gi = 0; gi < 2; ++gi)
#pragma unroll
        for (int ii = 0; ii < 4; ++ii) {
            const int i = gi * 4 + ii;
            const int row = m0 + ty4 + ii + gi * 64;
            float* dst = &cur[(size_t)row * H + n0 + tx4];
            *reinterpret_cast<float4*>(dst)      = make_float4(acc[i][0], acc[i][1], acc[i][2], acc[i][3]);
            *reinterpret_cast<float4*>(dst + 64) = make_float4(acc[i][4], acc[i][5], acc[i][6], acc[i][7]);
        }
}

// ---------------------------------------------------------------------------
// Kernel 3: sequential LSNN scan. One block per batch, 256 thr x 4 neurons.
//   R12: merged flat spike list (R9) + a MINIMAL 2-deep x 16-row gather
//   pipeline engineered against the R9/R10 spill failures:
//     - buffers wA[16], wB[16] = 128 VGPRs total (R9: 192, R10: 96+loop mess)
//     - NO conditionals inside the rotation body: row indices are CLAMPED to
//       0 when pos >= n (always-safe loads; row 0 is cache-hot), boundary
//       tile accumulated with fmaf(mask,w,r) (exact: fmaf(0,w,r)=r,
//       fmaf(1,w,r)=r+w), full tiles use plain adds behind a scalar-uniform
//       branch.
//     - list padded to 1088 so clamped tile index reads stay in-bounds.
//     - tile-0 loads issue at step top; latency hides under dynamics +
//       ballot + 2 barriers. n is carried in a register across steps.
//   Accumulation order (flat list = wave 0..3 ascending, rows ascending)
//   and all dynamics FP ops are bit-identical to R8 (absmax 0.0).
// ---------------------------------------------------------------------------
__global__ __launch_bounds__(256, 1) void lsnn_scan_kernel(float* __restrict__ io,
                                                           const float* __restrict__ wrecT) {
    const int b = blockIdx.x;
    const int tid = threadIdx.x;
    const int wave = tid >> 6, lane = tid & 63;
    const int j0 = tid * 4;

    __shared__ __align__(16) int list[2][1088];   // [phase][slot] merged list (+64 pad)
    __shared__ __align__(16) int cnt[2][4];       // [phase][wave] per-wave counts

    float sv0 = 0.f, sv1 = 0.f, sv2 = 0.f, sv3 = 0.f;
    float si0 = 0.f, si1 = 0.f, si2 = 0.f, si3 = 0.f;
    float sb0 = 1.f, sb1 = 1.f, sb2 = 1.f, sb3 = 1.f;
    float sz0 = 0.f, sz1 = 0.f, sz2 = 0.f, sz3 = 0.f;
    int p = 0;
    int n_carry = 0;

    const float C_MEM = (float)(1e-3 * 100.0);
    const float C_SYN = (float)(1e-3 * 200.0);
    const float C_AD  = (float)(1e-3 * (1.0 / 800.0));
    const float BETA  = 1.8f;

    float* base = io + (size_t)b * H + j0;

    if (lane == 0) cnt[0][wave] = 0;
    asm volatile("s_waitcnt lgkmcnt(0)" ::: "memory");
    __builtin_amdgcn_s_barrier();

    // chunk prefetch buffers: 8 steps of cur
    f32x4 P0 = *reinterpret_cast<const f32x4*>(base + (size_t)0 * BH);
    f32x4 P1 = *reinterpret_cast<const f32x4*>(base + (size_t)1 * BH);
    f32x4 P2 = *reinterpret_cast<const f32x4*>(base + (size_t)2 * BH);
    f32x4 P3 = *reinterpret_cast<const f32x4*>(base + (size_t)3 * BH);
    f32x4 P4 = *reinterpret_cast<const f32x4*>(base + (size_t)4 * BH);
    f32x4 P5 = *reinterpret_cast<const f32x4*>(base + (size_t)5 * BH);
    f32x4 P6 = *reinterpret_cast<const f32x4*>(base + (size_t)6 * BH);
    f32x4 P7 = *reinterpret_cast<const f32x4*>(base + (size_t)7 * BH);

// one row load, clamped: positions >= n read row 0 (safe, cache-hot, masked later)
#define ROWLD(DST, POS, HV)                                                   \
    { const int hc_ = ((POS) < n) ? (HV) : 0;                                 \
      DST = *(const f32x4*)(wrecT +                                           \
            (size_t)(unsigned)__builtin_amdgcn_readfirstlane(hc_) * H + j0); }

// load 16-row tile KT of the flat list (unconditional, clamped)
#define LOAD16C(BUF, KT)                                                      \
  { const int A0_ = (KT) << 4;                                                \
    const int4 q0_ = *reinterpret_cast<const int4*>(lst + A0_);               \
    const int4 q1_ = *reinterpret_cast<const int4*>(lst + A0_ + 4);           \
    const int4 q2_ = *reinterpret_cast<const int4*>(lst + A0_ + 8);           \
    const int4 q3_ = *reinterpret_cast<const int4*>(lst + A0_ + 12);          \
    ROWLD(BUF[0],  A0_ + 0,  q0_.x) ROWLD(BUF[1],  A0_ + 1,  q0_.y)           \
    ROWLD(BUF[2],  A0_ + 2,  q0_.z) ROWLD(BUF[3],  A0_ + 3,  q0_.w)           \
    ROWLD(BUF[4],  A0_ + 4,  q1_.x) ROWLD(BUF[5],  A0_ + 5,  q1_.y)           \
    ROWLD(BUF[6],  A0_ + 6,  q1_.z) ROWLD(BUF[7],  A0_ + 7,  q1_.w)           \
    ROWLD(BUF[8],  A0_ + 8,  q2_.x) ROWLD(BUF[9],  A0_ + 9,  q2_.y)           \
    ROWLD(BUF[10], A0_ + 10, q2_.z) ROWLD(BUF[11], A0_ + 11, q2_.w)           \
    ROWLD(BUF[12], A0_ + 12, q3_.x) ROWLD(BUF[13], A0_ + 13, q3_.y)           \
    ROWLD(BUF[14], A0_ + 14, q3_.z) ROWLD(BUF[15], A0_ + 15, q3_.w)           \
  }

#define ACC16(BUF)                                                            \
  { _Pragma("unroll")                                                         \
    for (int k_ = 0; k_ < 16; ++k_) {                                         \
      r0 += BUF[k_].x; r1 += BUF[k_].y; r2 += BUF[k_].z; r3 += BUF[k_].w;     \
    } }

#define ACC16M(BUF, KT)                                                       \
  { const int A0m_ = (KT) << 4;                                               \
    _Pragma("unroll")                                                         \
    for (int k_ = 0; k_ < 16; ++k_) {                                         \
      const float m_ = (A0m_ + k_ < n) ? 1.0f : 0.0f;                         \
      r0 = fmaf(m_, BUF[k_].x, r0); r1 = fmaf(m_, BUF[k_].y, r1);             \
      r2 = fmaf(m_, BUF[k_].z, r2); r3 = fmaf(m_, BUF[k_].w, r3);             \
    } }

// full tiles: plain adds (scalar-uniform branch); boundary tile: masked fmaf
#define ACCTILE(BUF, KT)                                                      \
  { if (((((KT) << 4)) + 16) <= n) { ACC16(BUF) } else { ACC16M(BUF, KT) } }

#define SCAN_STEP(T, CREG, PF)                                                \
  {                                                                           \
    const float cc0 = CREG.x, cc1 = CREG.y, cc2 = CREG.z, cc3 = CREG.w;       \
    const int n = __builtin_amdgcn_readfirstlane(n_carry);                    \
    const int NT = (n + 15) >> 4;                                             \
    const int* lst = &list[p][0];                                             \
    f32x4 wA[16], wB[16];                                                     \
    float r0 = 0.f, r1 = 0.f, r2 = 0.f, r3 = 0.f;                             \
    /* prologue: issue tile 0 before dynamics/ballot/barriers */              \
    LOAD16C(wA, 0);                                                           \
    /* dynamics (independent of this step's gather) */                        \
    const float vd0 = sv0 + C_MEM * (0.0f - sv0 + si0);                       \
    const float vd1 = sv1 + C_MEM * (0.0f - sv1 + si1);                       \
    const float vd2 = sv2 + C_MEM * (0.0f - sv2 + si2);                       \
    const float vd3 = sv3 + C_MEM * (0.0f - sv3 + si3);                       \
    const float id0 = si0 - C_SYN * si0;                                      \
    const float id1 = si1 - C_SYN * si1;                                      \
    const float id2 = si2 - C_SYN * si2;                                      \
    const float id3 = si3 - C_SYN * si3;                                      \
    const float bd0 = sb0 + C_AD * (1.0f - sb0);                              \
    const float bd1 = sb1 + C_AD * (1.0f - sb1);                              \
    const float bd2 = sb2 + C_AD * (1.0f - sb2);                              \
    const float bd3 = sb3 + C_AD * (1.0f - sb3);                              \
    sz0 = ((vd0 - bd0) > 0.0f) ? 1.0f : 0.0f;                                 \
    sz1 = ((vd1 - bd1) > 0.0f) ? 1.0f : 0.0f;                                 \
    sz2 = ((vd2 - bd2) > 0.0f) ? 1.0f : 0.0f;                                 \
    sz3 = ((vd3 - bd3) > 0.0f) ? 1.0f : 0.0f;                                 \
    sv0 = (sz0 > 0.0f) ? 0.0f : vd0;                                          \
    sv1 = (sz1 > 0.0f) ? 0.0f : vd1;                                          \
    sv2 = (sz2 > 0.0f) ? 0.0f : vd2;                                          \
    sv3 = (sz3 > 0.0f) ? 0.0f : vd3;                                          \
    sb0 = (sz0 > 0.0f) ? (bd0 + BETA) : bd0;                                  \
    sb1 = (sz1 > 0.0f) ? (bd1 + BETA) : bd1;                                  \
    sb2 = (sz2 > 0.0f) ? (bd2 + BETA) : bd2;                                  \
    sb3 = (sz3 > 0.0f) ? (bd3 + BETA) : bd3;                                  \
    *reinterpret_cast<f32x4*>(base + (size_t)(T) * BH) =                      \
        (f32x4){sz0, sz1, sz2, sz3};                                          \
    const unsigned long long m0 = __ballot(sz0 > 0.0f);                       \
    const unsigned long long m1 = __ballot(sz1 > 0.0f);                       \
    const unsigned long long m2 = __ballot(sz2 > 0.0f);                       \
    const unsigned long long m3 = __ballot(sz3 > 0.0f);                       \
    unsigned pos = __builtin_amdgcn_mbcnt_hi((unsigned)(m0 >> 32),            \
                   __builtin_amdgcn_mbcnt_lo((unsigned)m0, 0u));              \
    pos = __builtin_amdgcn_mbcnt_hi((unsigned)(m1 >> 32),                     \
          __builtin_amdgcn_mbcnt_lo((unsigned)m1, pos));                      \
    pos = __builtin_amdgcn_mbcnt_hi((unsigned)(m2 >> 32),                     \
          __builtin_amdgcn_mbcnt_lo((unsigned)m2, pos));                      \
    pos = __builtin_amdgcn_mbcnt_hi((unsigned)(m3 >> 32),                     \
          __builtin_amdgcn_mbcnt_lo((unsigned)m3, pos));                      \
    if (lane == 0)                                                            \
      cnt[p ^ 1][wave] = __popcll(m0) + __popcll(m1) + __popcll(m2) + __popcll(m3); \
    asm volatile("s_waitcnt lgkmcnt(0)" ::: "memory");                        \
    __builtin_amdgcn_s_barrier();                                             \
    /* cross-wave prefix -> write entries into merged list; carry next n */   \
    const int4 nc = *reinterpret_cast<const int4*>(&cnt[p ^ 1][0]);           \
    n_carry = nc.x + nc.y + nc.z + nc.w;                                      \
    const int woff = (wave > 0 ? nc.x : 0) + (wave > 1 ? nc.y : 0) +          \
                     (wave > 2 ? nc.z : 0);                                   \
    int* dst = &list[p ^ 1][woff];                                            \
    if (sz0 > 0.0f) dst[pos++] = j0 + 0;                                      \
    if (sz1 > 0.0f) dst[pos++] = j0 + 1;                                      \
    if (sz2 > 0.0f) dst[pos++] = j0 + 2;                                      \
    if (sz3 > 0.0f) dst[pos++] = j0 + 3;                                      \
    asm volatile("s_waitcnt lgkmcnt(0)" ::: "memory");                        \
    __builtin_amdgcn_s_barrier();                                             \
    /* 2-deep x 16-row pipelined gather, branch-free rotation body */         \
    if (n > 0) {                                                              \
      LOAD16C(wB, 1);                                                         \
      int kt = 0;                                                             \
      for (; kt + 2 < NT; kt += 2) {                                          \
        ACCTILE(wA, kt);     LOAD16C(wA, kt + 2);                             \
        ACCTILE(wB, kt + 1); LOAD16C(wB, kt + 3);                             \
      }                                                                       \
      ACCTILE(wA, kt);                                                        \
      if (kt + 1 < NT) ACCTILE(wB, kt + 1);                                   \
    }                                                                         \
    if (PF) {                                                                 \
      if ((T) + 1 < T_STEPS) {                                                \
        const float* pb = base + (size_t)((T) + 1) * BH;                      \
        P0 = *(const f32x4*)(pb + (size_t)0 * BH);                            \
        P1 = *(const f32x4*)(pb + (size_t)1 * BH);                            \
        P2 = *(const f32x4*)(pb + (size_t)2 * BH);                            \
        P3 = *(const f32x4*)(pb + (size_t)3 * BH);                            \
        P4 = *(const f32x4*)(pb + (size_t)4 * BH);                            \
        P5 = *(const f32x4*)(pb + (size_t)5 * BH);                            \
        P6 = *(const f32x4*)(pb + (size_t)6 * BH);                            \
        P7 = *(const f32x4*)(pb + (size_t)7 * BH);                            \
      }                                                                       \
    }                                                                         \
    si0 = (id0 + cc0) + r0;                                                   \
    si1 = (id1 + cc1) + r1;                                                   \
    si2 = (id2 + cc2) + r2;                                                   \
    si3 = (id3 + cc3) + r3;                                                   \
    p ^= 1;                                                                   \
  }

    for (int t = 0; t < T_STEPS; t += 8) {
        SCAN_STEP(t,     P0, 0);
        SCAN_STEP(t + 1, P1, 0);
        SCAN_STEP(t + 2, P2, 0);
        SCAN_STEP(t + 3, P3, 0);
        SCAN_STEP(t + 4, P4, 0);
        SCAN_STEP(t + 5, P5, 0);
        SCAN_STEP(t + 6, P6, 0);
        SCAN_STEP(t + 7, P7, 1);
    }
#undef SCAN_STEP
#undef ACCTILE
#undef ACC16M
#undef ACC16
#undef LOAD16C
#undef ROWLD

    float* fo = io + (size_t)T_STEPS * BH + (size_t)b * H + j0;
    *reinterpret_cast<float4*>(fo)          = make_float4(sz0, sz1, sz2, sz3);
    *reinterpret_cast<float4*>(fo + BH)     = make_float4(sv0, sv1, sv2, sv3);
    *reinterpret_cast<float4*>(fo + 2 * BH) = make_float4(si0, si1, si2, si3);
    *reinterpret_cast<float4*>(fo + 3 * BH) = make_float4(sb0, sb1, sb2, sb3);
}

// ---------------------------------------------------------------------------
extern "C" void kernel_launch(void* const* d_in, const int* in_sizes, int n_in,
                              void* d_out, int out_size, void* d_ws, size_t ws_size,
                              hipStream_t stream) {
    const float* x     = (const float*)d_in[0];
    const float* w_in  = (const float*)d_in[1];
    const float* w_rec = (const float*)d_in[2];
    float* out   = (float*)d_out;
    float* wrecT = (float*)d_ws;

    transpose1024<<<dim3(H / 32, H / 32), dim3(32, 8), 0, stream>>>(w_rec, wrecT);
    gemm_xwin<<<dim3(H / BN, (T_STEPS * BATCH) / BM), 256, 0, stream>>>(x, w_in, out);
    lsnn_scan_kernel<<<BATCH, 256, 0, stream>>>(out, wrecT);
}